// Round 7
// baseline (498.553 us; speedup 1.0000x reference)
//
#include <hip/hip_runtime.h>
#include <hip/hip_bf16.h>
#include <math.h>

#define N_NODES 50000
#define N_EDGES 800000
#define DIM 128
#define CLS 32
#define NGRAPH 64
#define LN_EPS 1e-5f
// padded CSR capacity: sum ceil(deg/8)*8 <= E + 7*N
#define CSR_CAP (N_EDGES + 8 * N_NODES)
#define NBLK ((N_NODES + 255) / 256)     // 196 scan blocks == 196 dst-buckets
#define EPB (N_EDGES / 256)              // 3125 edges per phase-A block
#define EB_STRIDE 5120                   // per-bucket ebuf capacity (mean 4096, +16 sigma)
#define LCAP 8192                        // per-bucket LDS csr capacity (padded <= ~4800)

typedef __attribute__((ext_vector_type(8))) short bf16x8;
typedef __attribute__((ext_vector_type(4))) float f32x4;

static __device__ __forceinline__ int lower_bound_i(const int* a, int n, int key) {
    int lo = 0, hi = n;
    while (lo < hi) { int mid = (lo + hi) >> 1; if (a[mid] < key) lo = mid + 1; else hi = mid; }
    return lo;
}

// ---- fused prep: zero scratch + bf16 convert + weight transpose ------------

__global__ __launch_bounds__(256) void prep_kernel(
    const float* __restrict__ x, const float* __restrict__ Wself,
    const float* __restrict__ Wmsg, __hip_bfloat16* __restrict__ XbIn,
    __hip_bfloat16* __restrict__ WT, int* __restrict__ counts,
    int* __restrict__ ecur,
    __hip_bfloat16* __restrict__ padA, __hip_bfloat16* __restrict__ padB,
    __hip_bfloat16* __restrict__ padC, __hip_bfloat16* __restrict__ padD) {
    int i = blockIdx.x * 256 + threadIdx.x;  // grid covers N_NODES*DIM/2 = 3.2M
    if (i < N_NODES * DIM / 2) {
        float2 v = ((const float2*)x)[i];
        ((__hip_bfloat162*)XbIn)[i] = __float22bfloat162_rn(v);
    }
    if (i < 3 * 128 * 256) {
        int l = i / (128 * 256);
        int rem = i - l * (128 * 256);
        int n = rem >> 8;
        int k = rem & 255;
        float v = (k < 128) ? Wself[l * 16384 + k * 128 + n]
                            : Wmsg[l * 16384 + (k - 128) * 128 + n];
        WT[i] = __float2bfloat16(v);
    }
    if (i < N_NODES) counts[i] = 0;
    if (i < NBLK) ecur[i] = i * EB_STRIDE;
    if (i < DIM) {
        padA[i] = __float2bfloat16(0.f);
        padB[i] = __float2bfloat16(0.f);
        padC[i] = __float2bfloat16(0.f);
        padD[i] = __float2bfloat16(0.f);
    }
}

// ---- phase A: histogram nodes (global) + bucket edges by dst>>8 ------------
// 256 blocks x 1024 threads, 3125 edges each. Per-block LDS bucket counts,
// ONE global atomic per (block,bucket) to reserve a contiguous ebuf range,
// then scatter packed entries ((dst&255)<<16 | src) in ~16-edge runs.

__global__ __launch_bounds__(1024) void bucket_kernel(
    const int* __restrict__ esrc, const int* __restrict__ edst,
    int* __restrict__ cnt, int* __restrict__ ecur, int* __restrict__ ebuf) {
    __shared__ int bc[NBLK];  // counts, then cursors (global positions)
    const int t = threadIdx.x;
    const int e0 = blockIdx.x * EPB;
    if (t < NBLK) bc[t] = 0;
    __syncthreads();
    for (int i = t; i < EPB; i += 1024) {
        int d = edst[e0 + i];
        atomicAdd(&cnt[d], 1);          // node histogram (for scan/off/deg)
        atomicAdd(&bc[d >> 8], 1);      // bucket histogram (LDS)
    }
    __syncthreads();
    if (t < NBLK) {
        int c = bc[t];
        bc[t] = atomicAdd(&ecur[t], c);  // reserve contiguous range
    }
    __syncthreads();
    for (int i = t; i < EPB; i += 1024) {
        int d = edst[e0 + i];
        int s = esrc[e0 + i];
        int pos = atomicAdd(&bc[d >> 8], 1);
        ebuf[pos] = ((d & 255) << 16) | s;  // src < 50000 < 2^16
    }
}

// ---- scans: padded exclusive scan of counts -> off[] -----------------------

__global__ __launch_bounds__(256) void scan_part1_kernel(const int* __restrict__ cnt,
                                                         int* __restrict__ bsum) {
    __shared__ int sd[256];
    int gi = blockIdx.x * 256 + threadIdx.x;
    int v = (gi < N_NODES) ? ((cnt[gi] + 7) & ~7) : 0;
    sd[threadIdx.x] = v;
    __syncthreads();
    for (int o = 128; o > 0; o >>= 1) {
        if (threadIdx.x < o) sd[threadIdx.x] += sd[threadIdx.x + o];
        __syncthreads();
    }
    if (threadIdx.x == 0) bsum[blockIdx.x] = sd[0];
}

__global__ __launch_bounds__(256) void scan_part2_kernel(int* __restrict__ bsum) {
    __shared__ int sd[256];
    int i = threadIdx.x;
    int v = (i < NBLK) ? bsum[i] : 0;
    sd[i] = v;
    __syncthreads();
    for (int o = 1; o < 256; o <<= 1) {
        int t = (i >= o) ? sd[i - o] : 0;
        __syncthreads();
        sd[i] += t;
        __syncthreads();
    }
    if (i < NBLK) bsum[i] = sd[i] - v;  // exclusive bucket base (padded)
}

__global__ __launch_bounds__(256) void scan_part3_kernel(const int* __restrict__ cnt,
                                                         const int* __restrict__ bsum,
                                                         int* __restrict__ off) {
    __shared__ int sd[256];
    int gi = blockIdx.x * 256 + threadIdx.x;
    int i = threadIdx.x;
    int c = (gi < N_NODES) ? cnt[gi] : 0;
    int v = (c + 7) & ~7;  // padded
    sd[i] = v;
    __syncthreads();
    for (int o = 1; o < 256; o <<= 1) {
        int t = (i >= o) ? sd[i - o] : 0;
        __syncthreads();
        sd[i] += t;
        __syncthreads();
    }
    int incl = sd[i];
    int base = bsum[blockIdx.x];
    if (gi < N_NODES) off[gi] = base + incl - v;
    if (gi == N_NODES - 1) off[N_NODES] = base + incl;
}

// ---- phase B: per-bucket CSR build entirely in LDS, coalesced writeout -----
// 196 blocks x 1024 threads. No global atomics, no random global stores.

__global__ __launch_bounds__(1024) void csr_build_kernel(
    const int* __restrict__ ebuf, const int* __restrict__ ecur,
    const int* __restrict__ bsum, int* __restrict__ csr) {
    __shared__ int ncnt[256];   // node counts -> cursors
    __shared__ int ssc[256];    // padded scan
    __shared__ int lcsr[LCAP];  // local csr segment
    const int b = blockIdx.x;
    const int t = threadIdx.x;
    const int bsize = ecur[b] - b * EB_STRIDE;
    const int* eb = ebuf + b * EB_STRIDE;
    for (int i = t; i < LCAP; i += 1024) lcsr[i] = N_NODES;  // pads -> zero row
    if (t < 256) ncnt[t] = 0;
    __syncthreads();
    for (int i = t; i < bsize; i += 1024) atomicAdd(&ncnt[eb[i] >> 16], 1);
    __syncthreads();
    int mypad = 0;
    if (t < 256) { mypad = (ncnt[t] + 7) & ~7; ssc[t] = mypad; }
    __syncthreads();
    for (int o = 1; o < 256; o <<= 1) {
        int v = 0;
        if (t < 256 && t >= o) v = ssc[t - o];
        __syncthreads();
        if (t < 256) ssc[t] += v;
        __syncthreads();
    }
    if (t < 256) ncnt[t] = ssc[t] - mypad;  // exclusive padded offset = cursor
    __syncthreads();
    for (int i = t; i < bsize; i += 1024) {
        int p = eb[i];
        int pos = atomicAdd(&ncnt[p >> 16], 1);
        if (pos < LCAP) lcsr[pos] = p & 0xFFFF;
    }
    __syncthreads();
    const int total = ssc[255];       // padded total, multiple of 8
    const int gbase = bsum[b];        // multiple of 8
    int4* dst4 = (int4*)(csr + gbase);
    const int4* src4 = (const int4*)lcsr;
    for (int i = t; i < (total >> 2); i += 1024) dst4[i] = src4[i];
}

// ---- Neighbor sum: Sb[n,:] = sum_{e in CSR[n]} Xb[src[e],:] (bf16 in/out) --
// One wave per node; 16 independent gathers in flight (8-edge tail); fp32 acc.

__global__ __launch_bounds__(256) void agg_kernel(const __hip_bfloat16* __restrict__ Xb,
                                                  const int* __restrict__ off,
                                                  const int* __restrict__ csr,
                                                  __hip_bfloat16* __restrict__ Sb) {
    int wave = threadIdx.x >> 6;
    int lane = threadIdx.x & 63;
    int n = blockIdx.x * 4 + wave;
    if (n >= N_NODES) return;
    int b = off[n], e = off[n + 1];  // padded: (e-b) % 8 == 0
    float ax = 0.f, ay = 0.f;
    const size_t coloff = (size_t)(lane * 2);
    int base = b;
    for (; base + 16 <= e; base += 16) {
        int idx16 = csr[base + (lane & 15)];
        int s[16];
        unsigned int v[16];
#pragma unroll
        for (int j = 0; j < 16; j++) s[j] = __shfl(idx16, j, 64);
#pragma unroll
        for (int j = 0; j < 16; j++)
            v[j] = *(const unsigned int*)(Xb + (size_t)s[j] * DIM + coloff);
#pragma unroll
        for (int j = 0; j < 16; j++) {
            union { unsigned int u; float f; } lo, hi;
            lo.u = v[j] << 16;
            hi.u = v[j] & 0xffff0000u;
            ax += lo.f;
            ay += hi.f;
        }
    }
    if (base < e) {  // 8-edge tail
        int idx8 = csr[base + (lane & 7)];
        int s[8];
        unsigned int v[8];
#pragma unroll
        for (int j = 0; j < 8; j++) s[j] = __shfl(idx8, j, 64);
#pragma unroll
        for (int j = 0; j < 8; j++)
            v[j] = *(const unsigned int*)(Xb + (size_t)s[j] * DIM + coloff);
#pragma unroll
        for (int j = 0; j < 8; j++) {
            union { unsigned int u; float f; } lo, hi;
            lo.u = v[j] << 16;
            hi.u = v[j] & 0xffff0000u;
            ax += lo.f;
            ay += hi.f;
        }
    }
    ((__hip_bfloat162*)(Sb + (size_t)n * DIM))[lane] =
        __float22bfloat162_rn(make_float2(ax, ay));
}

// ---- Fused layer via MFMA: H = [Xb|Sb] @ WT^T; +bias+deg*bmsg, ReLU, LN ----

__global__ __launch_bounds__(256) void layer_mfma_kernel(
    const __hip_bfloat16* __restrict__ Xb, const __hip_bfloat16* __restrict__ Sb,
    const __hip_bfloat16* __restrict__ WT,  // [128 n][256 k] bf16 for this layer
    const float* __restrict__ bself, const float* __restrict__ bmsg,
    const int* __restrict__ deg,
    const float* __restrict__ lng, const float* __restrict__ lnb,
    __hip_bfloat16* __restrict__ XoutB, int do_ln) {
    // stride 136 bf16 = 272 B (16B-aligned rows, 2-way bank aliasing = free)
    __shared__ __hip_bfloat16 wlds[128 * 136];
    const int tid = threadIdx.x;
    const int w = tid >> 6, lane = tid & 63;
    const int l15 = lane & 15, q = lane >> 4;

    const int row = blockIdx.x * 64 + w * 16 + l15;
    const int rowc = min(row, N_NODES);  // pad row N_NODES is all zeros

    f32x4 acc[8];
#pragma unroll
    for (int ct = 0; ct < 8; ct++) acc[ct] = (f32x4){0.f, 0.f, 0.f, 0.f};

    const __hip_bfloat16* Abase[2] = {Xb, Sb};
    for (int c = 0; c < 2; c++) {
        __syncthreads();  // protect previous chunk's LDS reads
        {
            // stage WT[n][c*128 .. c*128+127] -> wlds[n][0..127]
            // 256 threads x 8 uint4 (128 B) = 32 KB = 128 rows x 128 bf16
            int n = tid >> 1, h = tid & 1;
            const uint4* src = (const uint4*)(WT + n * 256 + c * 128 + h * 64);
            uint4* dst = (uint4*)(&wlds[n * 136 + h * 64]);
#pragma unroll
            for (int i = 0; i < 8; i++) dst[i] = src[i];
        }
        __syncthreads();
        const __hip_bfloat16* arow = Abase[c] + (size_t)rowc * DIM;
#pragma unroll
        for (int ks = 0; ks < 4; ks++) {
            bf16x8 afrag = *(const bf16x8*)(arow + ks * 32 + q * 8);
#pragma unroll
            for (int ct = 0; ct < 8; ct++) {
                bf16x8 bfrag = *(const bf16x8*)(&wlds[(ct * 16 + l15) * 136 + ks * 32 + q * 8]);
                acc[ct] = __builtin_amdgcn_mfma_f32_16x16x32_bf16(afrag, bfrag, acc[ct], 0, 0, 0);
            }
        }
    }

    // epilogue: lane holds rows (q*4+r), cols (ct*16+l15)
    const int growbase = blockIdx.x * 64 + w * 16;
#pragma unroll
    for (int r = 0; r < 4; r++) {
        int grow = growbase + q * 4 + r;
        bool valid = grow < N_NODES;
        float dg = valid ? (float)deg[grow] : 0.f;
        float v[8];
        float s1 = 0.f;
#pragma unroll
        for (int ct = 0; ct < 8; ct++) {
            int col = ct * 16 + l15;
            float h = acc[ct][r] + bself[col] + dg * bmsg[col];
            h = fmaxf(h, 0.f);
            v[ct] = h;
            s1 += h;
        }
        if (do_ln) {
#pragma unroll
            for (int m = 1; m < 16; m <<= 1) s1 += __shfl_xor(s1, m, 64);
            float mu = s1 * (1.0f / 128.0f);
            float s2 = 0.f;
#pragma unroll
            for (int ct = 0; ct < 8; ct++) { float d = v[ct] - mu; s2 += d * d; }
#pragma unroll
            for (int m = 1; m < 16; m <<= 1) s2 += __shfl_xor(s2, m, 64);
            float rs = rsqrtf(s2 * (1.0f / 128.0f) + LN_EPS);
#pragma unroll
            for (int ct = 0; ct < 8; ct++) {
                int col = ct * 16 + l15;
                v[ct] = lng[col] * (v[ct] - mu) * rs + lnb[col];
            }
        }
        if (valid) {
#pragma unroll
            for (int ct = 0; ct < 8; ct++) {
                int col = ct * 16 + l15;
                XoutB[(size_t)grow * DIM + col] = __float2bfloat16(v[ct]);
            }
        }
    }
}

// ---- fused mean pool + MLP head + log_softmax (one block per graph) --------

__global__ __launch_bounds__(128) void pool_head_kernel(
    const __hip_bfloat16* __restrict__ X, const int* __restrict__ batch,
    const float* __restrict__ W1, const float* __restrict__ b1,
    const float* __restrict__ W2, const float* __restrict__ b2,
    float* __restrict__ out) {
    __shared__ float p[128];
    __shared__ float hh[128];
    int g = blockIdx.x;
    int j = threadIdx.x;
    int lo = lower_bound_i(batch, N_NODES, g);
    int hi = lower_bound_i(batch, N_NODES, g + 1);
    float acc = 0.f;
    for (int n = lo; n < hi; n++) acc += __bfloat162float(X[(size_t)n * DIM + j]);
    float cnt = fmaxf((float)(hi - lo), 1.0f);
    p[j] = acc / cnt;
    __syncthreads();
    float s = b1[j];
    for (int k = 0; k < DIM; k++) s += p[k] * W1[k * DIM + j];
    hh[j] = s;
    __syncthreads();
    if (j < CLS) {
        float l = b2[j];
        for (int k = 0; k < DIM; k++) l += hh[k] * W2[k * CLS + j];
        float mx = l;
#pragma unroll
        for (int m = 16; m >= 1; m >>= 1) mx = fmaxf(mx, __shfl_xor(mx, m, 64));
        float ex = expf(l - mx);
        float se = ex;
#pragma unroll
        for (int m = 16; m >= 1; m >>= 1) se += __shfl_xor(se, m, 64);
        out[g * CLS + j] = l - mx - logf(se);
    }
}

// ---- launch ----------------------------------------------------------------

extern "C" void kernel_launch(void* const* d_in, const int* in_sizes, int n_in,
                              void* d_out, int out_size, void* d_ws, size_t ws_size,
                              hipStream_t stream) {
    (void)in_sizes; (void)n_in; (void)out_size; (void)ws_size;
    const float* x     = (const float*)d_in[0];
    const float* Wself = (const float*)d_in[1];
    const float* bself = (const float*)d_in[2];
    const float* Wmsg  = (const float*)d_in[3];
    const float* bmsg  = (const float*)d_in[4];
    const float* lng   = (const float*)d_in[5];
    const float* lnb   = (const float*)d_in[6];
    const float* W1    = (const float*)d_in[7];
    const float* b1    = (const float*)d_in[8];
    const float* W2    = (const float*)d_in[9];
    const float* b2    = (const float*)d_in[10];
    const int*   ei    = (const int*)d_in[11];
    const int*   batch = (const int*)d_in[12];
    const int* esrc = ei;
    const int* edst = ei + N_EDGES;

    char* w = (char*)d_ws;
    size_t o = 0;
    auto alloc = [&](size_t bytes) { void* p = w + o; o += (bytes + 255) & ~(size_t)255; return p; };
    __hip_bfloat16* XbIn = (__hip_bfloat16*)alloc((size_t)(N_NODES + 1) * DIM * 2);
    __hip_bfloat16* Xb0  = (__hip_bfloat16*)alloc((size_t)(N_NODES + 1) * DIM * 2);
    __hip_bfloat16* Xb1  = (__hip_bfloat16*)alloc((size_t)(N_NODES + 1) * DIM * 2);
    __hip_bfloat16* Sb   = (__hip_bfloat16*)alloc((size_t)(N_NODES + 1) * DIM * 2);
    __hip_bfloat16* WT   = (__hip_bfloat16*)alloc((size_t)3 * 128 * 256 * 2);
    int*   counts = (int*)alloc((size_t)N_NODES * 4);
    int*   offs   = (int*)alloc((size_t)(N_NODES + 1) * 4);
    int*   bsum   = (int*)alloc((size_t)NBLK * 4);
    int*   ecur   = (int*)alloc((size_t)NBLK * 4);
    int*   ebuf   = (int*)alloc((size_t)NBLK * EB_STRIDE * 4);
    int*   csr    = (int*)alloc((size_t)CSR_CAP * 4);

    // fused prep: bf16 convert + WT transpose + zero counts/ecur/pad rows
    prep_kernel<<<(N_NODES * DIM / 2 + 255) / 256, 256, 0, stream>>>(
        x, Wself, Wmsg, XbIn, WT, counts, ecur,
        XbIn + (size_t)N_NODES * DIM, Xb0 + (size_t)N_NODES * DIM,
        Xb1 + (size_t)N_NODES * DIM, Sb + (size_t)N_NODES * DIM);

    // CSR build: bucket (with fused node hist) -> scans -> LDS-local build
    bucket_kernel<<<256, 1024, 0, stream>>>(esrc, edst, counts, ecur, ebuf);
    scan_part1_kernel<<<NBLK, 256, 0, stream>>>(counts, bsum);
    scan_part2_kernel<<<1, 256, 0, stream>>>(bsum);
    scan_part3_kernel<<<NBLK, 256, 0, stream>>>(counts, bsum, offs);
    csr_build_kernel<<<NBLK, 1024, 0, stream>>>(ebuf, ecur, bsum, csr);

    const __hip_bfloat16* XbCur = XbIn;
    __hip_bfloat16* bbufs[3] = {Xb0, Xb1, Xb0};
    for (int i = 0; i < 3; i++) {
        agg_kernel<<<(N_NODES + 3) / 4, 256, 0, stream>>>(XbCur, offs, csr, Sb);
        layer_mfma_kernel<<<(N_NODES + 63) / 64, 256, 0, stream>>>(
            XbCur, Sb, WT + (size_t)i * 128 * 256,
            bself + i * DIM, bmsg + i * DIM, counts,
            (i < 2) ? lng + i * DIM : lng, (i < 2) ? lnb + i * DIM : lnb,
            bbufs[i], (i < 2) ? 1 : 0);
        XbCur = bbufs[i];
    }

    pool_head_kernel<<<NGRAPH, 128, 0, stream>>>(bbufs[2], batch, W1, b1, W2, b2,
                                                 (float*)d_out);
}

// Round 8
// 324.002 us; speedup vs baseline: 1.5387x; 1.5387x over previous
//
#include <hip/hip_runtime.h>
#include <hip/hip_bf16.h>
#include <math.h>

#define N_NODES 50000
#define N_EDGES 800000
#define DIM 128
#define CLS 32
#define NGRAPH 64
#define LN_EPS 1e-5f
// padded CSR capacity: sum ceil(deg/8)*8 <= E + 7*N
#define CSR_CAP (N_EDGES + 8 * N_NODES)
#define NBLK ((N_NODES + 255) / 256)     // 196 scan blocks == 196 dst-buckets
#define EPB (N_EDGES / 256)              // 3125 edges per phase-A block
#define EB_STRIDE 5120                   // per-bucket ebuf capacity (mean 4096, +16 sigma)
#define LCAP 8192                        // per-bucket LDS csr capacity (padded <= ~4800)
#define PSPLIT 16                        // pool partial splits per graph

typedef __attribute__((ext_vector_type(8))) short bf16x8;
typedef __attribute__((ext_vector_type(4))) float f32x4;

static __device__ __forceinline__ int lower_bound_i(const int* a, int n, int key) {
    int lo = 0, hi = n;
    while (lo < hi) { int mid = (lo + hi) >> 1; if (a[mid] < key) lo = mid + 1; else hi = mid; }
    return lo;
}

// ---- fused prep: zero scratch + bf16 convert + weight transpose ------------

__global__ __launch_bounds__(256) void prep_kernel(
    const float* __restrict__ x, const float* __restrict__ Wself,
    const float* __restrict__ Wmsg, __hip_bfloat16* __restrict__ XbIn,
    __hip_bfloat16* __restrict__ WT, int* __restrict__ counts,
    int* __restrict__ ecur, float* __restrict__ gsum,
    __hip_bfloat16* __restrict__ padA, __hip_bfloat16* __restrict__ padB,
    __hip_bfloat16* __restrict__ padC, __hip_bfloat16* __restrict__ padD) {
    int i = blockIdx.x * 256 + threadIdx.x;  // grid covers N_NODES*DIM/2 = 3.2M
    if (i < N_NODES * DIM / 2) {
        float2 v = ((const float2*)x)[i];
        ((__hip_bfloat162*)XbIn)[i] = __float22bfloat162_rn(v);
    }
    if (i < 3 * 128 * 256) {
        int l = i / (128 * 256);
        int rem = i - l * (128 * 256);
        int n = rem >> 8;
        int k = rem & 255;
        float v = (k < 128) ? Wself[l * 16384 + k * 128 + n]
                            : Wmsg[l * 16384 + (k - 128) * 128 + n];
        WT[i] = __float2bfloat16(v);
    }
    if (i < N_NODES) counts[i] = 0;
    if (i < NBLK) ecur[i] = i * EB_STRIDE;
    if (i < NGRAPH * DIM) gsum[i] = 0.f;
    if (i < DIM) {
        padA[i] = __float2bfloat16(0.f);
        padB[i] = __float2bfloat16(0.f);
        padC[i] = __float2bfloat16(0.f);
        padD[i] = __float2bfloat16(0.f);
    }
}

// ---- phase A: histogram nodes (global) + bucket edges by dst>>8 ------------
// 256 blocks x 1024 threads, 3125 edges each. Per-block LDS bucket counts,
// ONE global atomic per (block,bucket) to reserve a contiguous ebuf range,
// then scatter packed entries ((dst&255)<<16 | src) in ~16-edge runs.

__global__ __launch_bounds__(1024) void bucket_kernel(
    const int* __restrict__ esrc, const int* __restrict__ edst,
    int* __restrict__ cnt, int* __restrict__ ecur, int* __restrict__ ebuf) {
    __shared__ int bc[NBLK];  // counts, then cursors (global positions)
    const int t = threadIdx.x;
    const int e0 = blockIdx.x * EPB;
    if (t < NBLK) bc[t] = 0;
    __syncthreads();
    for (int i = t; i < EPB; i += 1024) {
        int d = edst[e0 + i];
        atomicAdd(&cnt[d], 1);          // node histogram (for scan/off/deg)
        atomicAdd(&bc[d >> 8], 1);      // bucket histogram (LDS)
    }
    __syncthreads();
    if (t < NBLK) {
        int c = bc[t];
        bc[t] = atomicAdd(&ecur[t], c);  // reserve contiguous range
    }
    __syncthreads();
    for (int i = t; i < EPB; i += 1024) {
        int d = edst[e0 + i];
        int s = esrc[e0 + i];
        int pos = atomicAdd(&bc[d >> 8], 1);
        ebuf[pos] = ((d & 255) << 16) | s;  // src < 50000 < 2^16
    }
}

// ---- scans: padded exclusive scan of counts -> off[] -----------------------

__global__ __launch_bounds__(256) void scan_part1_kernel(const int* __restrict__ cnt,
                                                         int* __restrict__ bsum) {
    __shared__ int sd[256];
    int gi = blockIdx.x * 256 + threadIdx.x;
    int v = (gi < N_NODES) ? ((cnt[gi] + 7) & ~7) : 0;
    sd[threadIdx.x] = v;
    __syncthreads();
    for (int o = 128; o > 0; o >>= 1) {
        if (threadIdx.x < o) sd[threadIdx.x] += sd[threadIdx.x + o];
        __syncthreads();
    }
    if (threadIdx.x == 0) bsum[blockIdx.x] = sd[0];
}

__global__ __launch_bounds__(256) void scan_part2_kernel(int* __restrict__ bsum) {
    __shared__ int sd[256];
    int i = threadIdx.x;
    int v = (i < NBLK) ? bsum[i] : 0;
    sd[i] = v;
    __syncthreads();
    for (int o = 1; o < 256; o <<= 1) {
        int t = (i >= o) ? sd[i - o] : 0;
        __syncthreads();
        sd[i] += t;
        __syncthreads();
    }
    if (i < NBLK) bsum[i] = sd[i] - v;  // exclusive bucket base (padded)
}

__global__ __launch_bounds__(256) void scan_part3_kernel(const int* __restrict__ cnt,
                                                         const int* __restrict__ bsum,
                                                         int* __restrict__ off) {
    __shared__ int sd[256];
    int gi = blockIdx.x * 256 + threadIdx.x;
    int i = threadIdx.x;
    int c = (gi < N_NODES) ? cnt[gi] : 0;
    int v = (c + 7) & ~7;  // padded
    sd[i] = v;
    __syncthreads();
    for (int o = 1; o < 256; o <<= 1) {
        int t = (i >= o) ? sd[i - o] : 0;
        __syncthreads();
        sd[i] += t;
        __syncthreads();
    }
    int incl = sd[i];
    int base = bsum[blockIdx.x];
    if (gi < N_NODES) off[gi] = base + incl - v;
    if (gi == N_NODES - 1) off[N_NODES] = base + incl;
}

// ---- phase B: per-bucket CSR build entirely in LDS, coalesced writeout -----
// 196 blocks x 1024 threads. No global atomics, no random global stores.

__global__ __launch_bounds__(1024) void csr_build_kernel(
    const int* __restrict__ ebuf, const int* __restrict__ ecur,
    const int* __restrict__ bsum, int* __restrict__ csr) {
    __shared__ int ncnt[256];   // node counts -> cursors
    __shared__ int ssc[256];    // padded scan
    __shared__ int lcsr[LCAP];  // local csr segment
    const int b = blockIdx.x;
    const int t = threadIdx.x;
    const int bsize = ecur[b] - b * EB_STRIDE;
    const int* eb = ebuf + b * EB_STRIDE;
    for (int i = t; i < LCAP; i += 1024) lcsr[i] = N_NODES;  // pads -> zero row
    if (t < 256) ncnt[t] = 0;
    __syncthreads();
    for (int i = t; i < bsize; i += 1024) atomicAdd(&ncnt[eb[i] >> 16], 1);
    __syncthreads();
    int mypad = 0;
    if (t < 256) { mypad = (ncnt[t] + 7) & ~7; ssc[t] = mypad; }
    __syncthreads();
    for (int o = 1; o < 256; o <<= 1) {
        int v = 0;
        if (t < 256 && t >= o) v = ssc[t - o];
        __syncthreads();
        if (t < 256) ssc[t] += v;
        __syncthreads();
    }
    if (t < 256) ncnt[t] = ssc[t] - mypad;  // exclusive padded offset = cursor
    __syncthreads();
    for (int i = t; i < bsize; i += 1024) {
        int p = eb[i];
        int pos = atomicAdd(&ncnt[p >> 16], 1);
        if (pos < LCAP) lcsr[pos] = p & 0xFFFF;
    }
    __syncthreads();
    const int total = ssc[255];       // padded total, multiple of 8
    const int gbase = bsum[b];        // multiple of 8
    int4* dst4 = (int4*)(csr + gbase);
    const int4* src4 = (const int4*)lcsr;
    for (int i = t; i < (total >> 2); i += 1024) dst4[i] = src4[i];
}

// ---- Neighbor sum: Sb[n,:] = sum_{e in CSR[n]} Xb[src[e],:] (bf16 in/out) --
// One wave per node; 16 independent gathers in flight (8-edge tail); fp32 acc.

__global__ __launch_bounds__(256) void agg_kernel(const __hip_bfloat16* __restrict__ Xb,
                                                  const int* __restrict__ off,
                                                  const int* __restrict__ csr,
                                                  __hip_bfloat16* __restrict__ Sb) {
    int wave = threadIdx.x >> 6;
    int lane = threadIdx.x & 63;
    int n = blockIdx.x * 4 + wave;
    if (n >= N_NODES) return;
    int b = off[n], e = off[n + 1];  // padded: (e-b) % 8 == 0
    float ax = 0.f, ay = 0.f;
    const size_t coloff = (size_t)(lane * 2);
    int base = b;
    for (; base + 16 <= e; base += 16) {
        int idx16 = csr[base + (lane & 15)];
        int s[16];
        unsigned int v[16];
#pragma unroll
        for (int j = 0; j < 16; j++) s[j] = __shfl(idx16, j, 64);
#pragma unroll
        for (int j = 0; j < 16; j++)
            v[j] = *(const unsigned int*)(Xb + (size_t)s[j] * DIM + coloff);
#pragma unroll
        for (int j = 0; j < 16; j++) {
            union { unsigned int u; float f; } lo, hi;
            lo.u = v[j] << 16;
            hi.u = v[j] & 0xffff0000u;
            ax += lo.f;
            ay += hi.f;
        }
    }
    if (base < e) {  // 8-edge tail
        int idx8 = csr[base + (lane & 7)];
        int s[8];
        unsigned int v[8];
#pragma unroll
        for (int j = 0; j < 8; j++) s[j] = __shfl(idx8, j, 64);
#pragma unroll
        for (int j = 0; j < 8; j++)
            v[j] = *(const unsigned int*)(Xb + (size_t)s[j] * DIM + coloff);
#pragma unroll
        for (int j = 0; j < 8; j++) {
            union { unsigned int u; float f; } lo, hi;
            lo.u = v[j] << 16;
            hi.u = v[j] & 0xffff0000u;
            ax += lo.f;
            ay += hi.f;
        }
    }
    ((__hip_bfloat162*)(Sb + (size_t)n * DIM))[lane] =
        __float22bfloat162_rn(make_float2(ax, ay));
}

// ---- Fused layer via MFMA: H = [Xb|Sb] @ WT^T; +bias+deg*bmsg, ReLU, LN ----

__global__ __launch_bounds__(256) void layer_mfma_kernel(
    const __hip_bfloat16* __restrict__ Xb, const __hip_bfloat16* __restrict__ Sb,
    const __hip_bfloat16* __restrict__ WT,  // [128 n][256 k] bf16 for this layer
    const float* __restrict__ bself, const float* __restrict__ bmsg,
    const int* __restrict__ deg,
    const float* __restrict__ lng, const float* __restrict__ lnb,
    __hip_bfloat16* __restrict__ XoutB, int do_ln) {
    // stride 136 bf16 = 272 B (16B-aligned rows, 2-way bank aliasing = free)
    __shared__ __hip_bfloat16 wlds[128 * 136];
    const int tid = threadIdx.x;
    const int w = tid >> 6, lane = tid & 63;
    const int l15 = lane & 15, q = lane >> 4;

    const int row = blockIdx.x * 64 + w * 16 + l15;
    const int rowc = min(row, N_NODES);  // pad row N_NODES is all zeros

    f32x4 acc[8];
#pragma unroll
    for (int ct = 0; ct < 8; ct++) acc[ct] = (f32x4){0.f, 0.f, 0.f, 0.f};

    const __hip_bfloat16* Abase[2] = {Xb, Sb};
    for (int c = 0; c < 2; c++) {
        __syncthreads();  // protect previous chunk's LDS reads
        {
            // stage WT[n][c*128 .. c*128+127] -> wlds[n][0..127]
            // 256 threads x 8 uint4 (128 B) = 32 KB = 128 rows x 128 bf16
            int n = tid >> 1, h = tid & 1;
            const uint4* src = (const uint4*)(WT + n * 256 + c * 128 + h * 64);
            uint4* dst = (uint4*)(&wlds[n * 136 + h * 64]);
#pragma unroll
            for (int i = 0; i < 8; i++) dst[i] = src[i];
        }
        __syncthreads();
        const __hip_bfloat16* arow = Abase[c] + (size_t)rowc * DIM;
#pragma unroll
        for (int ks = 0; ks < 4; ks++) {
            bf16x8 afrag = *(const bf16x8*)(arow + ks * 32 + q * 8);
#pragma unroll
            for (int ct = 0; ct < 8; ct++) {
                bf16x8 bfrag = *(const bf16x8*)(&wlds[(ct * 16 + l15) * 136 + ks * 32 + q * 8]);
                acc[ct] = __builtin_amdgcn_mfma_f32_16x16x32_bf16(afrag, bfrag, acc[ct], 0, 0, 0);
            }
        }
    }

    // epilogue: lane holds rows (q*4+r), cols (ct*16+l15)
    const int growbase = blockIdx.x * 64 + w * 16;
#pragma unroll
    for (int r = 0; r < 4; r++) {
        int grow = growbase + q * 4 + r;
        bool valid = grow < N_NODES;
        float dg = valid ? (float)deg[grow] : 0.f;
        float v[8];
        float s1 = 0.f;
#pragma unroll
        for (int ct = 0; ct < 8; ct++) {
            int col = ct * 16 + l15;
            float h = acc[ct][r] + bself[col] + dg * bmsg[col];
            h = fmaxf(h, 0.f);
            v[ct] = h;
            s1 += h;
        }
        if (do_ln) {
#pragma unroll
            for (int m = 1; m < 16; m <<= 1) s1 += __shfl_xor(s1, m, 64);
            float mu = s1 * (1.0f / 128.0f);
            float s2 = 0.f;
#pragma unroll
            for (int ct = 0; ct < 8; ct++) { float d = v[ct] - mu; s2 += d * d; }
#pragma unroll
            for (int m = 1; m < 16; m <<= 1) s2 += __shfl_xor(s2, m, 64);
            float rs = rsqrtf(s2 * (1.0f / 128.0f) + LN_EPS);
#pragma unroll
            for (int ct = 0; ct < 8; ct++) {
                int col = ct * 16 + l15;
                v[ct] = lng[col] * (v[ct] - mu) * rs + lnb[col];
            }
        }
        if (valid) {
#pragma unroll
            for (int ct = 0; ct < 8; ct++) {
                int col = ct * 16 + l15;
                XoutB[(size_t)grow * DIM + col] = __float2bfloat16(v[ct]);
            }
        }
    }
}

// ---- Global mean pool (partial sums) + head --------------------------------

__global__ __launch_bounds__(128) void pool_partial_kernel(const __hip_bfloat16* __restrict__ X,
                                                           const int* __restrict__ batch,
                                                           float* __restrict__ gsum) {
    int g = blockIdx.x;
    int s = blockIdx.y;
    int lo = lower_bound_i(batch, N_NODES, g);
    int hi = lower_bound_i(batch, N_NODES, g + 1);
    int len = hi - lo;
    int a = lo + (int)(((long long)len * s) / PSPLIT);
    int b = lo + (int)(((long long)len * (s + 1)) / PSPLIT);
    int c = threadIdx.x;
    float acc = 0.f;
    for (int n = a; n < b; n++) acc += __bfloat162float(X[(size_t)n * DIM + c]);
    if (b > a) atomicAdd(&gsum[g * DIM + c], acc);
}

__global__ __launch_bounds__(128) void head_kernel(
    const float* __restrict__ gsum, const int* __restrict__ batch,
    const float* __restrict__ W1, const float* __restrict__ b1,
    const float* __restrict__ W2, const float* __restrict__ b2,
    float* __restrict__ out) {
    __shared__ float p[128];
    __shared__ float hh[128];
    int g = blockIdx.x;
    int j = threadIdx.x;
    int lo = lower_bound_i(batch, N_NODES, g);
    int hi = lower_bound_i(batch, N_NODES, g + 1);
    float cnt = fmaxf((float)(hi - lo), 1.0f);
    p[j] = gsum[g * DIM + j] / cnt;
    __syncthreads();
    float s = b1[j];
    for (int k = 0; k < DIM; k++) s += p[k] * W1[k * DIM + j];
    hh[j] = s;
    __syncthreads();
    if (j < CLS) {
        float l = b2[j];
        for (int k = 0; k < DIM; k++) l += hh[k] * W2[k * CLS + j];
        float mx = l;
#pragma unroll
        for (int m = 16; m >= 1; m >>= 1) mx = fmaxf(mx, __shfl_xor(mx, m, 64));
        float ex = expf(l - mx);
        float se = ex;
#pragma unroll
        for (int m = 16; m >= 1; m >>= 1) se += __shfl_xor(se, m, 64);
        out[g * CLS + j] = l - mx - logf(se);
    }
}

// ---- launch ----------------------------------------------------------------

extern "C" void kernel_launch(void* const* d_in, const int* in_sizes, int n_in,
                              void* d_out, int out_size, void* d_ws, size_t ws_size,
                              hipStream_t stream) {
    (void)in_sizes; (void)n_in; (void)out_size; (void)ws_size;
    const float* x     = (const float*)d_in[0];
    const float* Wself = (const float*)d_in[1];
    const float* bself = (const float*)d_in[2];
    const float* Wmsg  = (const float*)d_in[3];
    const float* bmsg  = (const float*)d_in[4];
    const float* lng   = (const float*)d_in[5];
    const float* lnb   = (const float*)d_in[6];
    const float* W1    = (const float*)d_in[7];
    const float* b1    = (const float*)d_in[8];
    const float* W2    = (const float*)d_in[9];
    const float* b2    = (const float*)d_in[10];
    const int*   ei    = (const int*)d_in[11];
    const int*   batch = (const int*)d_in[12];
    const int* esrc = ei;
    const int* edst = ei + N_EDGES;

    char* w = (char*)d_ws;
    size_t o = 0;
    auto alloc = [&](size_t bytes) { void* p = w + o; o += (bytes + 255) & ~(size_t)255; return p; };
    __hip_bfloat16* XbIn = (__hip_bfloat16*)alloc((size_t)(N_NODES + 1) * DIM * 2);
    __hip_bfloat16* Xb0  = (__hip_bfloat16*)alloc((size_t)(N_NODES + 1) * DIM * 2);
    __hip_bfloat16* Xb1  = (__hip_bfloat16*)alloc((size_t)(N_NODES + 1) * DIM * 2);
    __hip_bfloat16* Sb   = (__hip_bfloat16*)alloc((size_t)(N_NODES + 1) * DIM * 2);
    __hip_bfloat16* WT   = (__hip_bfloat16*)alloc((size_t)3 * 128 * 256 * 2);
    int*   counts = (int*)alloc((size_t)N_NODES * 4);
    int*   offs   = (int*)alloc((size_t)(N_NODES + 1) * 4);
    int*   bsum   = (int*)alloc((size_t)NBLK * 4);
    int*   ecur   = (int*)alloc((size_t)NBLK * 4);
    int*   ebuf   = (int*)alloc((size_t)NBLK * EB_STRIDE * 4);
    int*   csr    = (int*)alloc((size_t)CSR_CAP * 4);
    float* gsum   = (float*)alloc((size_t)NGRAPH * DIM * 4);

    // fused prep: bf16 convert + WT transpose + zero counts/ecur/gsum/pad rows
    prep_kernel<<<(N_NODES * DIM / 2 + 255) / 256, 256, 0, stream>>>(
        x, Wself, Wmsg, XbIn, WT, counts, ecur, gsum,
        XbIn + (size_t)N_NODES * DIM, Xb0 + (size_t)N_NODES * DIM,
        Xb1 + (size_t)N_NODES * DIM, Sb + (size_t)N_NODES * DIM);

    // CSR build: bucket (with fused node hist) -> scans -> LDS-local build
    bucket_kernel<<<256, 1024, 0, stream>>>(esrc, edst, counts, ecur, ebuf);
    scan_part1_kernel<<<NBLK, 256, 0, stream>>>(counts, bsum);
    scan_part2_kernel<<<1, 256, 0, stream>>>(bsum);
    scan_part3_kernel<<<NBLK, 256, 0, stream>>>(counts, bsum, offs);
    csr_build_kernel<<<NBLK, 1024, 0, stream>>>(ebuf, ecur, bsum, csr);

    const __hip_bfloat16* XbCur = XbIn;
    __hip_bfloat16* bbufs[3] = {Xb0, Xb1, Xb0};
    for (int i = 0; i < 3; i++) {
        agg_kernel<<<(N_NODES + 3) / 4, 256, 0, stream>>>(XbCur, offs, csr, Sb);
        layer_mfma_kernel<<<(N_NODES + 63) / 64, 256, 0, stream>>>(
            XbCur, Sb, WT + (size_t)i * 128 * 256,
            bself + i * DIM, bmsg + i * DIM, counts,
            (i < 2) ? lng + i * DIM : lng, (i < 2) ? lnb + i * DIM : lnb,
            bbufs[i], (i < 2) ? 1 : 0);
        XbCur = bbufs[i];
    }

    pool_partial_kernel<<<dim3(NGRAPH, PSPLIT), 128, 0, stream>>>(bbufs[2], batch, gsum);
    head_kernel<<<NGRAPH, 128, 0, stream>>>(gsum, batch, W1, b1, W2, b2, (float*)d_out);
}

// Round 9
// 294.500 us; speedup vs baseline: 1.6929x; 1.1002x over previous
//
#include <hip/hip_runtime.h>
#include <hip/hip_bf16.h>
#include <math.h>

#define N_NODES 50000
#define N_EDGES 800000
#define DIM 128
#define CLS 32
#define NGRAPH 64
#define LN_EPS 1e-5f
// padded CSR capacity: sum ceil(deg/8)*8 <= E + 7*N
#define CSR_CAP (N_EDGES + 8 * N_NODES)
#define NBLK 196                         // dst-buckets of 256 nodes
#define ABLK 128                         // phase-A blocks
#define EPB (N_EDGES / ABLK)             // 6250 edges per phase-A block
#define EB_STRIDE 7168                   // per-bucket ebuf capacity (mean ~5100 incl pads)
#define LCAP 8192                        // per-bucket LDS csr capacity (padded <= ~6200)
#define PSPLIT 16                        // pool partial splits per graph

typedef __attribute__((ext_vector_type(8))) short bf16x8;
typedef __attribute__((ext_vector_type(4))) float f32x4;

static __device__ __forceinline__ int lower_bound_i(const int* a, int n, int key) {
    int lo = 0, hi = n;
    while (lo < hi) { int mid = (lo + hi) >> 1; if (a[mid] < key) lo = mid + 1; else hi = mid; }
    return lo;
}

// ---- fused prep: zero scratch + bf16 convert + weight transpose ------------

__global__ __launch_bounds__(256) void prep_kernel(
    const float* __restrict__ x, const float* __restrict__ Wself,
    const float* __restrict__ Wmsg, __hip_bfloat16* __restrict__ XbIn,
    __hip_bfloat16* __restrict__ WT,
    int* __restrict__ ecur, float* __restrict__ gsum,
    __hip_bfloat16* __restrict__ padA, __hip_bfloat16* __restrict__ padB,
    __hip_bfloat16* __restrict__ padC, __hip_bfloat16* __restrict__ padD) {
    int i = blockIdx.x * 256 + threadIdx.x;  // grid covers N_NODES*DIM/2 = 3.2M
    if (i < N_NODES * DIM / 2) {
        float2 v = ((const float2*)x)[i];
        ((__hip_bfloat162*)XbIn)[i] = __float22bfloat162_rn(v);
    }
    if (i < 3 * 128 * 256) {
        int l = i / (128 * 256);
        int rem = i - l * (128 * 256);
        int n = rem >> 8;
        int k = rem & 255;
        float v = (k < 128) ? Wself[l * 16384 + k * 128 + n]
                            : Wmsg[l * 16384 + (k - 128) * 128 + n];
        WT[i] = __float2bfloat16(v);
    }
    if (i < NBLK) ecur[i] = i * EB_STRIDE;
    if (i < NGRAPH * DIM) gsum[i] = 0.f;
    if (i < DIM) {
        padA[i] = __float2bfloat16(0.f);
        padB[i] = __float2bfloat16(0.f);
        padC[i] = __float2bfloat16(0.f);
        padD[i] = __float2bfloat16(0.f);
    }
}

// ---- phase A: bucket edges by dst>>8, line-exclusive reservations ----------
// 128 blocks x 1024 threads, 6250 edges each. Reservations rounded to 16
// entries (one 64B line) so every ebuf line is written by exactly one block;
// gaps filled with -1 sentinels. NO global atomics on per-node counts.

__global__ __launch_bounds__(1024) void bucket_kernel(
    const int* __restrict__ esrc, const int* __restrict__ edst,
    int* __restrict__ ecur, int* __restrict__ ebuf) {
    __shared__ int bc[NBLK], bres[NBLK], bcnt[NBLK];
    const int t = threadIdx.x;
    const int e0 = blockIdx.x * EPB;
    if (t < NBLK) bc[t] = 0;
    __syncthreads();
    for (int i = t; i < EPB; i += 1024)
        atomicAdd(&bc[edst[e0 + i] >> 8], 1);
    __syncthreads();
    if (t < NBLK) {
        int c = bc[t];
        int r = (c + 15) & ~15;                 // whole 64B lines
        int res = atomicAdd(&ecur[t], r);       // one global atomic per (block,bucket)
        bres[t] = res;
        bcnt[t] = c;
        bc[t] = res;
    }
    __syncthreads();
    for (int i = t; i < EPB; i += 1024) {
        int d = edst[e0 + i];
        int s = esrc[e0 + i];
        int pos = atomicAdd(&bc[d >> 8], 1);
        ebuf[pos] = ((d & 255) << 16) | s;      // src < 50000 < 2^16
    }
    __syncthreads();
    if (t < NBLK) {
        int c = bcnt[t], r = (c + 15) & ~15, base = bres[t];
        for (int j = c; j < r; j++) ebuf[base + j] = -1;  // sentinels
    }
}

// ---- phase B1: per-bucket node histogram from ebuf (no global atomics) -----
// Writes counts[] (deg, coalesced) + padded bucket total btot[b].

__global__ __launch_bounds__(1024) void bhist_kernel(
    const int* __restrict__ ebuf, const int* __restrict__ ecur,
    int* __restrict__ counts, int* __restrict__ btot) {
    __shared__ int ncnt[256];
    __shared__ int red[256];
    const int b = blockIdx.x, t = threadIdx.x;
    const int used = ecur[b] - b * EB_STRIDE;
    const int* eb = ebuf + b * EB_STRIDE;
    if (t < 256) ncnt[t] = 0;
    __syncthreads();
    for (int i = t; i < used; i += 1024) {
        int p = eb[i];
        if (p != -1) atomicAdd(&ncnt[p >> 16], 1);
    }
    __syncthreads();
    if (t < 256) {
        int gi = b * 256 + t;
        if (gi < N_NODES) counts[gi] = ncnt[t];
        red[t] = (ncnt[t] + 7) & ~7;
    }
    __syncthreads();
    for (int o = 128; o > 0; o >>= 1) {
        if (t < o) red[t] += red[t + o];
        __syncthreads();
    }
    if (t == 0) btot[b] = red[0];
}

// ---- phase B2: exclusive scan of 196 padded bucket totals ------------------

__global__ __launch_bounds__(256) void btot_scan_kernel(const int* __restrict__ btot,
                                                        int* __restrict__ bbase,
                                                        int* __restrict__ off) {
    __shared__ int sd[256];
    int i = threadIdx.x;
    int v = (i < NBLK) ? btot[i] : 0;
    sd[i] = v;
    __syncthreads();
    for (int o = 1; o < 256; o <<= 1) {
        int tv = (i >= o) ? sd[i - o] : 0;
        __syncthreads();
        sd[i] += tv;
        __syncthreads();
    }
    if (i < NBLK) bbase[i] = sd[i] - v;  // exclusive
    if (i == 255) off[N_NODES] = sd[255];
}

// ---- phase B3: per-bucket CSR build in LDS; writes off[] + coalesced csr ---

__global__ __launch_bounds__(1024) void csr_build_kernel(
    const int* __restrict__ ebuf, const int* __restrict__ ecur,
    const int* __restrict__ counts, const int* __restrict__ bbase,
    int* __restrict__ off, int* __restrict__ csr) {
    __shared__ int cur[256];    // per-node cursors
    __shared__ int ssc[256];    // padded scan
    __shared__ int lcsr[LCAP];  // local csr segment
    const int b = blockIdx.x, t = threadIdx.x;
    const int used = ecur[b] - b * EB_STRIDE;
    const int* eb = ebuf + b * EB_STRIDE;
    const int gbase = bbase[b];
    for (int i = t; i < LCAP; i += 1024) lcsr[i] = N_NODES;  // pads -> zero row
    int myc = 0, mypad = 0;
    const int gi = b * 256 + t;
    if (t < 256) {
        myc = (gi < N_NODES) ? counts[gi] : 0;
        mypad = (myc + 7) & ~7;
        ssc[t] = mypad;
    }
    __syncthreads();
    for (int o = 1; o < 256; o <<= 1) {
        int v = 0;
        if (t < 256 && t >= o) v = ssc[t - o];
        __syncthreads();
        if (t < 256) ssc[t] += v;
        __syncthreads();
    }
    if (t < 256) {
        int eoff = ssc[t] - mypad;  // exclusive padded offset within bucket
        cur[t] = eoff;
        if (gi < N_NODES) off[gi] = gbase + eoff;
    }
    __syncthreads();
    for (int i = t; i < used; i += 1024) {
        int p = eb[i];
        if (p != -1) {
            int pos = atomicAdd(&cur[p >> 16], 1);
            lcsr[pos] = p & 0xFFFF;
        }
    }
    __syncthreads();
    const int total = ssc[255];       // padded total, multiple of 8
    int4* dst4 = (int4*)(csr + gbase);
    const int4* src4 = (const int4*)lcsr;
    for (int i = t; i < (total >> 2); i += 1024) dst4[i] = src4[i];
}

// ---- Neighbor sum: Sb[n,:] = sum_{e in CSR[n]} Xb[src[e],:] (bf16 in/out) --
// One wave per node; 16 independent gathers in flight (8-edge tail); fp32 acc.

__global__ __launch_bounds__(256) void agg_kernel(const __hip_bfloat16* __restrict__ Xb,
                                                  const int* __restrict__ off,
                                                  const int* __restrict__ csr,
                                                  __hip_bfloat16* __restrict__ Sb) {
    int wave = threadIdx.x >> 6;
    int lane = threadIdx.x & 63;
    int n = blockIdx.x * 4 + wave;
    if (n >= N_NODES) return;
    int b = off[n], e = off[n + 1];  // padded: (e-b) % 8 == 0
    float ax = 0.f, ay = 0.f;
    const size_t coloff = (size_t)(lane * 2);
    int base = b;
    for (; base + 16 <= e; base += 16) {
        int idx16 = csr[base + (lane & 15)];
        int s[16];
        unsigned int v[16];
#pragma unroll
        for (int j = 0; j < 16; j++) s[j] = __shfl(idx16, j, 64);
#pragma unroll
        for (int j = 0; j < 16; j++)
            v[j] = *(const unsigned int*)(Xb + (size_t)s[j] * DIM + coloff);
#pragma unroll
        for (int j = 0; j < 16; j++) {
            union { unsigned int u; float f; } lo, hi;
            lo.u = v[j] << 16;
            hi.u = v[j] & 0xffff0000u;
            ax += lo.f;
            ay += hi.f;
        }
    }
    if (base < e) {  // 8-edge tail
        int idx8 = csr[base + (lane & 7)];
        int s[8];
        unsigned int v[8];
#pragma unroll
        for (int j = 0; j < 8; j++) s[j] = __shfl(idx8, j, 64);
#pragma unroll
        for (int j = 0; j < 8; j++)
            v[j] = *(const unsigned int*)(Xb + (size_t)s[j] * DIM + coloff);
#pragma unroll
        for (int j = 0; j < 8; j++) {
            union { unsigned int u; float f; } lo, hi;
            lo.u = v[j] << 16;
            hi.u = v[j] & 0xffff0000u;
            ax += lo.f;
            ay += hi.f;
        }
    }
    ((__hip_bfloat162*)(Sb + (size_t)n * DIM))[lane] =
        __float22bfloat162_rn(make_float2(ax, ay));
}

// ---- Fused layer via MFMA: H = [Xb|Sb] @ WT^T; +bias+deg*bmsg, ReLU, LN ----

__global__ __launch_bounds__(256) void layer_mfma_kernel(
    const __hip_bfloat16* __restrict__ Xb, const __hip_bfloat16* __restrict__ Sb,
    const __hip_bfloat16* __restrict__ WT,  // [128 n][256 k] bf16 for this layer
    const float* __restrict__ bself, const float* __restrict__ bmsg,
    const int* __restrict__ deg,
    const float* __restrict__ lng, const float* __restrict__ lnb,
    __hip_bfloat16* __restrict__ XoutB, int do_ln) {
    // stride 136 bf16 = 272 B (16B-aligned rows, 2-way bank aliasing = free)
    __shared__ __hip_bfloat16 wlds[128 * 136];
    const int tid = threadIdx.x;
    const int w = tid >> 6, lane = tid & 63;
    const int l15 = lane & 15, q = lane >> 4;

    const int row = blockIdx.x * 64 + w * 16 + l15;
    const int rowc = min(row, N_NODES);  // pad row N_NODES is all zeros

    f32x4 acc[8];
#pragma unroll
    for (int ct = 0; ct < 8; ct++) acc[ct] = (f32x4){0.f, 0.f, 0.f, 0.f};

    const __hip_bfloat16* Abase[2] = {Xb, Sb};
    for (int c = 0; c < 2; c++) {
        __syncthreads();  // protect previous chunk's LDS reads
        {
            // stage WT[n][c*128 .. c*128+127] -> wlds[n][0..127]
            int n = tid >> 1, h = tid & 1;
            const uint4* src = (const uint4*)(WT + n * 256 + c * 128 + h * 64);
            uint4* dst = (uint4*)(&wlds[n * 136 + h * 64]);
#pragma unroll
            for (int i = 0; i < 8; i++) dst[i] = src[i];
        }
        __syncthreads();
        const __hip_bfloat16* arow = Abase[c] + (size_t)rowc * DIM;
#pragma unroll
        for (int ks = 0; ks < 4; ks++) {
            bf16x8 afrag = *(const bf16x8*)(arow + ks * 32 + q * 8);
#pragma unroll
            for (int ct = 0; ct < 8; ct++) {
                bf16x8 bfrag = *(const bf16x8*)(&wlds[(ct * 16 + l15) * 136 + ks * 32 + q * 8]);
                acc[ct] = __builtin_amdgcn_mfma_f32_16x16x32_bf16(afrag, bfrag, acc[ct], 0, 0, 0);
            }
        }
    }

    // epilogue: lane holds rows (q*4+r), cols (ct*16+l15)
    const int growbase = blockIdx.x * 64 + w * 16;
#pragma unroll
    for (int r = 0; r < 4; r++) {
        int grow = growbase + q * 4 + r;
        bool valid = grow < N_NODES;
        float dg = valid ? (float)deg[grow] : 0.f;
        float v[8];
        float s1 = 0.f;
#pragma unroll
        for (int ct = 0; ct < 8; ct++) {
            int col = ct * 16 + l15;
            float h = acc[ct][r] + bself[col] + dg * bmsg[col];
            h = fmaxf(h, 0.f);
            v[ct] = h;
            s1 += h;
        }
        if (do_ln) {
#pragma unroll
            for (int m = 1; m < 16; m <<= 1) s1 += __shfl_xor(s1, m, 64);
            float mu = s1 * (1.0f / 128.0f);
            float s2 = 0.f;
#pragma unroll
            for (int ct = 0; ct < 8; ct++) { float d = v[ct] - mu; s2 += d * d; }
#pragma unroll
            for (int m = 1; m < 16; m <<= 1) s2 += __shfl_xor(s2, m, 64);
            float rs = rsqrtf(s2 * (1.0f / 128.0f) + LN_EPS);
#pragma unroll
            for (int ct = 0; ct < 8; ct++) {
                int col = ct * 16 + l15;
                v[ct] = lng[col] * (v[ct] - mu) * rs + lnb[col];
            }
        }
        if (valid) {
#pragma unroll
            for (int ct = 0; ct < 8; ct++) {
                int col = ct * 16 + l15;
                XoutB[(size_t)grow * DIM + col] = __float2bfloat16(v[ct]);
            }
        }
    }
}

// ---- Global mean pool (partial sums) + head --------------------------------

__global__ __launch_bounds__(128) void pool_partial_kernel(const __hip_bfloat16* __restrict__ X,
                                                           const int* __restrict__ batch,
                                                           float* __restrict__ gsum) {
    int g = blockIdx.x;
    int s = blockIdx.y;
    int lo = lower_bound_i(batch, N_NODES, g);
    int hi = lower_bound_i(batch, N_NODES, g + 1);
    int len = hi - lo;
    int a = lo + (int)(((long long)len * s) / PSPLIT);
    int b = lo + (int)(((long long)len * (s + 1)) / PSPLIT);
    int c = threadIdx.x;
    float acc = 0.f;
    for (int n = a; n < b; n++) acc += __bfloat162float(X[(size_t)n * DIM + c]);
    if (b > a) atomicAdd(&gsum[g * DIM + c], acc);
}

__global__ __launch_bounds__(128) void head_kernel(
    const float* __restrict__ gsum, const int* __restrict__ batch,
    const float* __restrict__ W1, const float* __restrict__ b1,
    const float* __restrict__ W2, const float* __restrict__ b2,
    float* __restrict__ out) {
    __shared__ float p[128];
    __shared__ float hh[128];
    int g = blockIdx.x;
    int j = threadIdx.x;
    int lo = lower_bound_i(batch, N_NODES, g);
    int hi = lower_bound_i(batch, N_NODES, g + 1);
    float cnt = fmaxf((float)(hi - lo), 1.0f);
    p[j] = gsum[g * DIM + j] / cnt;
    __syncthreads();
    float s = b1[j];
    for (int k = 0; k < DIM; k++) s += p[k] * W1[k * DIM + j];
    hh[j] = s;
    __syncthreads();
    if (j < CLS) {
        float l = b2[j];
        for (int k = 0; k < DIM; k++) l += hh[k] * W2[k * CLS + j];
        float mx = l;
#pragma unroll
        for (int m = 16; m >= 1; m >>= 1) mx = fmaxf(mx, __shfl_xor(mx, m, 64));
        float ex = expf(l - mx);
        float se = ex;
#pragma unroll
        for (int m = 16; m >= 1; m >>= 1) se += __shfl_xor(se, m, 64);
        out[g * CLS + j] = l - mx - logf(se);
    }
}

// ---- launch ----------------------------------------------------------------

extern "C" void kernel_launch(void* const* d_in, const int* in_sizes, int n_in,
                              void* d_out, int out_size, void* d_ws, size_t ws_size,
                              hipStream_t stream) {
    (void)in_sizes; (void)n_in; (void)out_size; (void)ws_size;
    const float* x     = (const float*)d_in[0];
    const float* Wself = (const float*)d_in[1];
    const float* bself = (const float*)d_in[2];
    const float* Wmsg  = (const float*)d_in[3];
    const float* bmsg  = (const float*)d_in[4];
    const float* lng   = (const float*)d_in[5];
    const float* lnb   = (const float*)d_in[6];
    const float* W1    = (const float*)d_in[7];
    const float* b1    = (const float*)d_in[8];
    const float* W2    = (const float*)d_in[9];
    const float* b2    = (const float*)d_in[10];
    const int*   ei    = (const int*)d_in[11];
    const int*   batch = (const int*)d_in[12];
    const int* esrc = ei;
    const int* edst = ei + N_EDGES;

    char* w = (char*)d_ws;
    size_t o = 0;
    auto alloc = [&](size_t bytes) { void* p = w + o; o += (bytes + 255) & ~(size_t)255; return p; };
    __hip_bfloat16* XbIn = (__hip_bfloat16*)alloc((size_t)(N_NODES + 1) * DIM * 2);
    __hip_bfloat16* Xb0  = (__hip_bfloat16*)alloc((size_t)(N_NODES + 1) * DIM * 2);
    __hip_bfloat16* Xb1  = (__hip_bfloat16*)alloc((size_t)(N_NODES + 1) * DIM * 2);
    __hip_bfloat16* Sb   = (__hip_bfloat16*)alloc((size_t)(N_NODES + 1) * DIM * 2);
    __hip_bfloat16* WT   = (__hip_bfloat16*)alloc((size_t)3 * 128 * 256 * 2);
    int*   counts = (int*)alloc((size_t)N_NODES * 4);
    int*   offs   = (int*)alloc((size_t)(N_NODES + 1) * 4);
    int*   btot   = (int*)alloc((size_t)NBLK * 4);
    int*   bbase  = (int*)alloc((size_t)NBLK * 4);
    int*   ecur   = (int*)alloc((size_t)NBLK * 4);
    int*   ebuf   = (int*)alloc((size_t)NBLK * EB_STRIDE * 4);
    int*   csr    = (int*)alloc((size_t)CSR_CAP * 4);
    float* gsum   = (float*)alloc((size_t)NGRAPH * DIM * 4);

    // fused prep: bf16 convert + WT transpose + zero ecur/gsum/pad rows
    prep_kernel<<<(N_NODES * DIM / 2 + 255) / 256, 256, 0, stream>>>(
        x, Wself, Wmsg, XbIn, WT, ecur, gsum,
        XbIn + (size_t)N_NODES * DIM, Xb0 + (size_t)N_NODES * DIM,
        Xb1 + (size_t)N_NODES * DIM, Sb + (size_t)N_NODES * DIM);

    // CSR build: bucket -> per-bucket hist -> bucket scan -> LDS-local build
    bucket_kernel<<<ABLK, 1024, 0, stream>>>(esrc, edst, ecur, ebuf);
    bhist_kernel<<<NBLK, 1024, 0, stream>>>(ebuf, ecur, counts, btot);
    btot_scan_kernel<<<1, 256, 0, stream>>>(btot, bbase, offs);
    csr_build_kernel<<<NBLK, 1024, 0, stream>>>(ebuf, ecur, counts, bbase, offs, csr);

    const __hip_bfloat16* XbCur = XbIn;
    __hip_bfloat16* bbufs[3] = {Xb0, Xb1, Xb0};
    for (int i = 0; i < 3; i++) {
        agg_kernel<<<(N_NODES + 3) / 4, 256, 0, stream>>>(XbCur, offs, csr, Sb);
        layer_mfma_kernel<<<(N_NODES + 63) / 64, 256, 0, stream>>>(
            XbCur, Sb, WT + (size_t)i * 128 * 256,
            bself + i * DIM, bmsg + i * DIM, counts,
            (i < 2) ? lng + i * DIM : lng, (i < 2) ? lnb + i * DIM : lnb,
            bbufs[i], (i < 2) ? 1 : 0);
        XbCur = bbufs[i];
    }

    pool_partial_kernel<<<dim3(NGRAPH, PSPLIT), 128, 0, stream>>>(bbufs[2], batch, gsum);
    head_kernel<<<NGRAPH, 128, 0, stream>>>(gsum, batch, W1, b1, W2, b2, (float*)d_out);
}